// Round 3
// baseline (2236.438 us; speedup 1.0000x reference)
//
#include <hip/hip_runtime.h>
#include <math.h>

#define H 512
#define GV 640
#define E_DIM 256
#define BM 64
#define KSTEP 32
#define NKT (H / KSTEP)   // 16

typedef _Float16 half8 __attribute__((ext_vector_type(8)));
typedef float f32x4 __attribute__((ext_vector_type(4)));

// ws layout
#define WS_WH 4096
#define WS_WL (4096 + 655360)
#define WS_NEED (4096 + 2 * 655360)

// ---------------- prep: W (640x512 f32) -> fp16 hi/lo images, fragment-order ----------------
// Granule t (16 B = half8): kt = t/2560, g = (t%2560)/640, col = t%640.
// Holds W[col][kt*32 + g*8 .. +8], hi scaled by 1024, lo by 1024*2048.
// A wave's B-fragment load (fixed kt,g,w,nt; q=0..15 varies) is then 16 consecutive
// granules = 256 B contiguous -> perfectly coalesced L2 hits.
__global__ void prep_w(const float* __restrict__ W, _Float16* __restrict__ wh,
                       _Float16* __restrict__ wl)
{
    int t = blockIdx.x * 256 + threadIdx.x;      // 0..40959
    int kt = t / 2560;
    int rem = t % 2560;
    int g = rem / 640;
    int col = rem - g * 640;
    int k = kt * KSTEP + g * 8;
    const float* src = W + (size_t)col * H + k;
    float4 v0 = *(const float4*)src;
    float4 v1 = *(const float4*)(src + 4);
    float vv[8] = {v0.x, v0.y, v0.z, v0.w, v1.x, v1.y, v1.z, v1.w};
    half8 hv, lv;
    #pragma unroll
    for (int i = 0; i < 8; ++i) {
        float ws_ = vv[i] * 1024.0f;
        _Float16 h = (_Float16)ws_;
        hv[i] = h;
        lv[i] = (_Float16)((ws_ - (float)h) * 2048.0f);
    }
    ((half8*)wh)[t] = hv;
    ((half8*)wl)[t] = lv;
}

// ---------------- main fused kernel ----------------
// 640 threads = 10 waves; wave w owns cols w*64..w*64+63 of all 64 rows.
// LDS only holds the X tile (hi/lo) -> 8.8 KB -> 3 blocks/CU co-resident.
// B-fragments stream directly from the L2-resident pre-swizzled W images.
__global__ __launch_bounds__(640, 8) void gemm_argmax_mfma(
    const float* __restrict__ hid,     // (B,512)
    const float* __restrict__ noise,   // (B,640)
    const float* __restrict__ emb,     // (640,256)
    const float* __restrict__ bias,    // (640)
    const _Float16* __restrict__ wh,
    const _Float16* __restrict__ wl,
    float* __restrict__ out,           // (B,512) + 1
    int* __restrict__ cnt)             // (640)
{
    __shared__ __align__(16) _Float16 Xh[BM][KSTEP];   // 4 KB
    __shared__ __align__(16) _Float16 Xl[BM][KSTEP];   // 4 KB
    __shared__ int sel_n[BM][2];

    float* red_val = (float*)&Xh[0][0];   // overlay after K-loop: [64][10]
    int*   red_idx = (int*)&Xl[0][0];     // overlay: [64][10]

    const int tid = threadIdx.x;
    const int w = tid >> 6;               // wave 0..9
    const int l = tid & 63;
    const int q = l & 15, g = l >> 4;
    const int sig = (q >> 1) & 3;         // X swizzle sigma for row mt*16+q
    const int sl = (g ^ sig) * 8;         // k-slot (in halves) for A-fragment reads
    const int brow = blockIdx.x * BM;

    f32x4 acc1[4][4], acc2[4][4];
    #pragma unroll
    for (int mt = 0; mt < 4; ++mt)
        #pragma unroll
        for (int nt = 0; nt < 4; ++nt) {
            acc1[mt][nt] = (f32x4){0.f, 0.f, 0.f, 0.f};
            acc2[mt][nt] = (f32x4){0.f, 0.f, 0.f, 0.f};
        }

    const half8* whv = (const half8*)wh;
    const half8* wlv = (const half8*)wl;

    for (int kt = 0; kt < NKT; ++kt) {
        __syncthreads();   // previous iteration's A-frag reads done before overwrite
        // ---- stage X: load f32, split to fp16 hi/lo (x*64 scale), swizzled write ----
        if (tid < 256) {
            int r = tid & 63, c = tid >> 6;
            const float* src = hid + (size_t)(brow + r) * H + kt * KSTEP + c * 8;
            float4 v0 = *(const float4*)src;
            float4 v1 = *(const float4*)(src + 4);
            float vv[8] = {v0.x, v0.y, v0.z, v0.w, v1.x, v1.y, v1.z, v1.w};
            half8 hv, lv;
            #pragma unroll
            for (int i = 0; i < 8; ++i) {
                float xs = vv[i] * 64.0f;
                _Float16 h = (_Float16)xs;
                hv[i] = h;
                lv[i] = (_Float16)((xs - (float)h) * 2048.0f);
            }
            int slot = c ^ ((r >> 1) & 3);
            *(half8*)&Xh[r][slot * 8] = hv;
            *(half8*)&Xl[r][slot * 8] = lv;
        }
        __syncthreads();

        // ---- A fragments from LDS (swizzled, 2-way max -> conflict-free) ----
        half8 Ah[4], Al[4];
        #pragma unroll
        for (int mt = 0; mt < 4; ++mt) {
            int row = mt * 16 + q;
            Ah[mt] = *(const half8*)&Xh[row][sl];
            Al[mt] = *(const half8*)&Xl[row][sl];
        }

        // ---- B fragments straight from L2-resident image + MFMA ----
        const int gbase = (kt * 4 + g) * 640 + w * 64 + q;
        #pragma unroll
        for (int nt = 0; nt < 4; ++nt) {
            half8 Bh = whv[gbase + nt * 16];
            half8 Bl = wlv[gbase + nt * 16];
            #pragma unroll
            for (int mt = 0; mt < 4; ++mt) {
                acc1[mt][nt] = __builtin_amdgcn_mfma_f32_16x16x32_f16(Ah[mt], Bh, acc1[mt][nt], 0, 0, 0);
                acc2[mt][nt] = __builtin_amdgcn_mfma_f32_16x16x32_f16(Ah[mt], Bl, acc2[mt][nt], 0, 0, 0);
                acc2[mt][nt] = __builtin_amdgcn_mfma_f32_16x16x32_f16(Al[mt], Bh, acc2[mt][nt], 0, 0, 0);
            }
        }
    }

    __syncthreads();   // all compute done; Xh/Xl reusable as reduction scratch

    // ---- epilogue: z = logits + bias + gumbel; per-row argmax ----
    const float C1 = 1.52587890625e-05f;        // 2^-16  (64*1024 product scale)
    const float C2 = 7.450580596923828e-09f;    // 2^-27
    float bcol[4];
    #pragma unroll
    for (int nt = 0; nt < 4; ++nt) bcol[nt] = bias[w * 64 + nt * 16 + q];

    #pragma unroll
    for (int mt = 0; mt < 4; ++mt) {
        #pragma unroll
        for (int reg = 0; reg < 4; ++reg) {
            int r = mt * 16 + 4 * g + reg;      // local row held by this lane
            float bv = -INFINITY;
            int bn = 0;
            #pragma unroll
            for (int nt = 0; nt < 4; ++nt) {
                int col = w * 64 + nt * 16 + q;
                float u = noise[(size_t)(brow + r) * GV + col];
                float gum = -logf(-logf(u + 1e-10f) + 1e-10f);
                float z = acc1[mt][nt][reg] * C1 + acc2[mt][nt][reg] * C2 + bcol[nt] + gum;
                if (z > bv) { bv = z; bn = col; }          // ascending col: first-wins
            }
            #pragma unroll
            for (int m = 1; m < 16; m <<= 1) {             // 16-lane argmax reduce
                float ov = __shfl_xor(bv, m, 64);
                int on = __shfl_xor(bn, m, 64);
                if (ov > bv || (ov == bv && on < bn)) { bv = ov; bn = on; }
            }
            if (q == 0) { red_val[r * 10 + w] = bv; red_idx[r * 10 + w] = bn; }
        }
    }
    __syncthreads();

    // ---- cross-wave reduce (5 waves per group, ascending col ranges) ----
    if (tid < 128) {
        int r = tid >> 1, grp = tid & 1;
        float bv = -INFINITY;
        int bn = 0;
        #pragma unroll
        for (int ww = 0; ww < 5; ++ww) {
            int wi = grp * 5 + ww;
            float v = red_val[r * 10 + wi];
            int n = red_idx[r * 10 + wi];
            if (v > bv) { bv = v; bn = n; }
        }
        atomicAdd(&cnt[bn], 1);
        sel_n[r][grp] = bn;
    }
    __syncthreads();

    // ---- gather selected embedding rows ----
    if (tid < 512) {
        int rg = tid >> 2, sub = tid & 3;
        int r = rg >> 1, grp = rg & 1;
        int n = sel_n[r][grp];
        const float4* src = (const float4*)(emb + (size_t)n * E_DIM);
        float4* dst = (float4*)(out + (size_t)(brow + r) * 512 + grp * 256);
        #pragma unroll
        for (int j = 0; j < 16; ++j)
            dst[sub + j * 4] = src[sub + j * 4];
    }
}

__global__ void ppl_kernel(const int* __restrict__ cnt, float* __restrict__ outp)
{
    const int lane = threadIdx.x;
    float total = 0.f;
    #pragma unroll
    for (int gg = 0; gg < 2; ++gg) {
        float s = 0.f;
        for (int v = lane; v < 320; v += 64) {
            float m = (float)cnt[gg * 320 + v] * (1.0f / 65536.0f);
            s += m * logf(m + 1e-7f);
        }
        #pragma unroll
        for (int msk = 1; msk <= 32; msk <<= 1) s += __shfl_xor(s, msk, 64);
        total += expf(-s);
    }
    if (lane == 0) *outp = total;
}

// ---------------- fallback fp32 path (round-1 kernel, used if ws too small) ----------------
__global__ __launch_bounds__(512) void fused_gemm_argmax(
    const float* __restrict__ hid, const float* __restrict__ noise,
    const float* __restrict__ emb, const float* __restrict__ W,
    const float* __restrict__ bias, float* __restrict__ out, int* __restrict__ cnt)
{
    __shared__ float A_lds[16][64];
    __shared__ float B_lds[16][GV + 4];
    const int tid = threadIdx.x;
    const int tx = tid & 63, ty = tid >> 6;
    const int brow = blockIdx.x * 64;
    const int nbase = tx * 10;
    float acc[8][10];
    #pragma unroll
    for (int i = 0; i < 8; ++i)
        #pragma unroll
        for (int j = 0; j < 10; ++j) acc[i][j] = 0.f;
    for (int t = 0; t < H; t += 16) {
        if (t) __syncthreads();
        if (tid < 256) {
            int m = tid & 63, kq = tid >> 6;
            float4 v = *(const float4*)(hid + (size_t)(brow + m) * H + t + kq * 4);
            A_lds[kq * 4 + 0][m] = v.x; A_lds[kq * 4 + 1][m] = v.y;
            A_lds[kq * 4 + 2][m] = v.z; A_lds[kq * 4 + 3][m] = v.w;
        }
        #pragma unroll
        for (int s = 0; s < 5; ++s) {
            int c = tid + s * 512;
            int n = c % 640, kq = c / 640;
            float4 v = *(const float4*)(W + (size_t)n * H + t + kq * 4);
            B_lds[kq * 4 + 0][n] = v.x; B_lds[kq * 4 + 1][n] = v.y;
            B_lds[kq * 4 + 2][n] = v.z; B_lds[kq * 4 + 3][n] = v.w;
        }
        __syncthreads();
        #pragma unroll 4
        for (int kk = 0; kk < 16; ++kk) {
            float a[8], bb[10];
            #pragma unroll
            for (int i = 0; i < 8; ++i) a[i] = A_lds[kk][ty * 8 + i];
            #pragma unroll
            for (int j = 0; j < 10; ++j) bb[j] = B_lds[kk][nbase + j];
            #pragma unroll
            for (int i = 0; i < 8; ++i)
                #pragma unroll
                for (int j = 0; j < 10; ++j) acc[i][j] = fmaf(a[i], bb[j], acc[i][j]);
        }
    }
    float bs[10];
    #pragma unroll
    for (int j = 0; j < 10; ++j) bs[j] = bias[nbase + j];
    const int gg = tx >> 5, ll = tx & 31;
    #pragma unroll
    for (int i = 0; i < 8; ++i) {
        const int b = brow + ty * 8 + i;
        float best = -INFINITY; int bestn = nbase;
        #pragma unroll
        for (int j = 0; j < 10; ++j) {
            float u = noise[(size_t)b * GV + nbase + j];
            float gmb = -logf(-logf(u + 1e-10f) + 1e-10f);
            float z = acc[i][j] + bs[j] + gmb;
            if (z > best) { best = z; bestn = nbase + j; }
        }
        #pragma unroll
        for (int msk = 1; msk <= 16; msk <<= 1) {
            float oz = __shfl_xor(best, msk, 64);
            int on = __shfl_xor(bestn, msk, 64);
            if (oz > best || (oz == best && on < bestn)) { best = oz; bestn = on; }
        }
        if (ll == 0) atomicAdd(&cnt[bestn], 1);
        const float4* src = (const float4*)(emb + (size_t)bestn * E_DIM);
        float4* dst = (float4*)(out + (size_t)b * 512 + gg * 256);
        dst[ll] = src[ll];
        dst[ll + 32] = src[ll + 32];
    }
}

extern "C" void kernel_launch(void* const* d_in, const int* in_sizes, int n_in,
                              void* d_out, int out_size, void* d_ws, size_t ws_size,
                              hipStream_t stream)
{
    const float* hid   = (const float*)d_in[0];
    const float* noise = (const float*)d_in[1];
    const float* emb   = (const float*)d_in[2];
    const float* W     = (const float*)d_in[3];
    const float* bias  = (const float*)d_in[4];
    float* out = (float*)d_out;
    int* cnt = (int*)d_ws;
    const int B = in_sizes[0] / H;

    hipMemsetAsync(cnt, 0, GV * sizeof(int), stream);
    if (ws_size >= (size_t)WS_NEED) {
        _Float16* wh = (_Float16*)((char*)d_ws + WS_WH);
        _Float16* wl = (_Float16*)((char*)d_ws + WS_WL);
        prep_w<<<160, 256, 0, stream>>>(W, wh, wl);
        gemm_argmax_mfma<<<B / BM, 640, 0, stream>>>(hid, noise, emb, bias, wh, wl, out, cnt);
    } else {
        fused_gemm_argmax<<<B / BM, 512, 0, stream>>>(hid, noise, emb, W, bias, out, cnt);
    }
    ppl_kernel<<<1, 64, 0, stream>>>(cnt, out + (size_t)B * 512);
}

// Round 4
// 280.894 us; speedup vs baseline: 7.9619x; 7.9619x over previous
//
#include <hip/hip_runtime.h>
#include <math.h>

#define H 512
#define GV 640
#define E_DIM 256
#define BM 64
#define KSTEP 32
#define NKT (H / KSTEP)   // 16

typedef _Float16 half8 __attribute__((ext_vector_type(8)));
typedef float f32x4 __attribute__((ext_vector_type(4)));

// ws layout
#define WS_WH 4096
#define WS_WL (4096 + 655360)
#define WS_NEED (4096 + 2 * 655360)

// ---------------- prep: W (640x512 f32) -> fp16 hi/lo images, fragment-order ----------------
// Granule t (16 B = half8): kt = t/2560, g = (t%2560)/640, col = t%640.
// Holds W[col][kt*32 + g*8 .. +8] scaled by 1024; lo = UNSCALED residual (same 2^16
// product scale as hi*hi -> single accumulator).
__global__ void prep_w(const float* __restrict__ W, _Float16* __restrict__ wh,
                       _Float16* __restrict__ wl)
{
    int t = blockIdx.x * 256 + threadIdx.x;      // 0..40959
    int kt = t / 2560;
    int rem = t % 2560;
    int g = rem / 640;
    int col = rem - g * 640;
    int k = kt * KSTEP + g * 8;
    const float* src = W + (size_t)col * H + k;
    float4 v0 = *(const float4*)src;
    float4 v1 = *(const float4*)(src + 4);
    float vv[8] = {v0.x, v0.y, v0.z, v0.w, v1.x, v1.y, v1.z, v1.w};
    half8 hv, lv;
    #pragma unroll
    for (int i = 0; i < 8; ++i) {
        float ws_ = vv[i] * 1024.0f;
        _Float16 h = (_Float16)ws_;
        hv[i] = h;
        lv[i] = (_Float16)(ws_ - (float)h);      // unscaled residual
    }
    ((half8*)wh)[t] = hv;
    ((half8*)wl)[t] = lv;
}

// ---------------- main fused kernel ----------------
// 640 threads = 10 waves; wave w owns cols w*64..w*64+63 of all 64 rows.
// LDS holds only the X tile (hi/lo) = 8.7 KB; B streams from L2-resident images.
// Single f32x4 acc[4][4] per thread: all three split-products share the 2^16 scale.
__global__ __launch_bounds__(640) void gemm_argmax_mfma(
    const float* __restrict__ hid,     // (B,512)
    const float* __restrict__ noise,   // (B,640)
    const float* __restrict__ emb,     // (640,256)
    const float* __restrict__ bias,    // (640)
    const _Float16* __restrict__ wh,
    const _Float16* __restrict__ wl,
    float* __restrict__ out,           // (B,512) + 1
    int* __restrict__ cnt)             // (640)
{
    __shared__ __align__(16) _Float16 Xh[BM][KSTEP];   // 4 KB
    __shared__ __align__(16) _Float16 Xl[BM][KSTEP];   // 4 KB
    __shared__ int sel_n[BM][2];

    float* red_val = (float*)&Xh[0][0];   // overlay after K-loop: [64][10]
    int*   red_idx = (int*)&Xl[0][0];     // overlay: [64][10]

    const int tid = threadIdx.x;
    const int w = tid >> 6;               // wave 0..9
    const int l = tid & 63;
    const int q = l & 15, g = l >> 4;
    const int sig = (q >> 1) & 3;         // X swizzle sigma for row mt*16+q
    const int sl = (g ^ sig) * 8;         // k-slot (in halves) for A-fragment reads
    const int brow = blockIdx.x * BM;

    f32x4 acc[4][4];
    #pragma unroll
    for (int mt = 0; mt < 4; ++mt)
        #pragma unroll
        for (int nt = 0; nt < 4; ++nt)
            acc[mt][nt] = (f32x4){0.f, 0.f, 0.f, 0.f};

    const half8* whv = (const half8*)wh;
    const half8* wlv = (const half8*)wl;

    for (int kt = 0; kt < NKT; ++kt) {
        __syncthreads();   // previous iteration's A-frag reads done before overwrite
        // ---- stage X: load f32, split to fp16 hi/lo (x*64 scale), swizzled write ----
        if (tid < 256) {
            int r = tid & 63, c = tid >> 6;
            const float* src = hid + (size_t)(brow + r) * H + kt * KSTEP + c * 8;
            float4 v0 = *(const float4*)src;
            float4 v1 = *(const float4*)(src + 4);
            float vv[8] = {v0.x, v0.y, v0.z, v0.w, v1.x, v1.y, v1.z, v1.w};
            half8 hv, lv;
            #pragma unroll
            for (int i = 0; i < 8; ++i) {
                float xs = vv[i] * 64.0f;
                _Float16 h = (_Float16)xs;
                hv[i] = h;
                lv[i] = (_Float16)(xs - (float)h);   // unscaled residual
            }
            int slot = c ^ ((r >> 1) & 3);
            *(half8*)&Xh[r][slot * 8] = hv;
            *(half8*)&Xl[r][slot * 8] = lv;
        }
        __syncthreads();

        // ---- A fragments from LDS (swizzled; measured 0 conflicts) ----
        half8 Ah[4], Al[4];
        #pragma unroll
        for (int mt = 0; mt < 4; ++mt) {
            int row = mt * 16 + q;
            Ah[mt] = *(const half8*)&Xh[row][sl];
            Al[mt] = *(const half8*)&Xl[row][sl];
        }

        // ---- B fragments straight from L2-resident image + 3-product MFMA ----
        const int gbase = (kt * 4 + g) * 640 + w * 64 + q;
        #pragma unroll
        for (int nt = 0; nt < 4; ++nt) {
            half8 Bh = whv[gbase + nt * 16];
            half8 Bl = wlv[gbase + nt * 16];
            #pragma unroll
            for (int mt = 0; mt < 4; ++mt) {
                acc[mt][nt] = __builtin_amdgcn_mfma_f32_16x16x32_f16(Ah[mt], Bh, acc[mt][nt], 0, 0, 0);
                acc[mt][nt] = __builtin_amdgcn_mfma_f32_16x16x32_f16(Ah[mt], Bl, acc[mt][nt], 0, 0, 0);
                acc[mt][nt] = __builtin_amdgcn_mfma_f32_16x16x32_f16(Al[mt], Bh, acc[mt][nt], 0, 0, 0);
            }
        }
    }

    __syncthreads();   // all compute done; Xh/Xl reusable as reduction scratch

    // ---- epilogue: z = logits + bias + gumbel; per-row argmax ----
    const float C1 = 1.52587890625e-05f;        // 2^-16  (64*1024 product scale)
    float bcol[4];
    #pragma unroll
    for (int nt = 0; nt < 4; ++nt) bcol[nt] = bias[w * 64 + nt * 16 + q];

    #pragma unroll
    for (int mt = 0; mt < 4; ++mt) {
        #pragma unroll
        for (int reg = 0; reg < 4; ++reg) {
            int r = mt * 16 + 4 * g + reg;      // local row held by this lane
            float bv = -INFINITY;
            int bn = 0;
            #pragma unroll
            for (int nt = 0; nt < 4; ++nt) {
                int col = w * 64 + nt * 16 + q;
                float u = noise[(size_t)(brow + r) * GV + col];
                float gum = -logf(-logf(u + 1e-10f) + 1e-10f);
                float z = acc[mt][nt][reg] * C1 + bcol[nt] + gum;
                if (z > bv) { bv = z; bn = col; }          // ascending col: first-wins
            }
            #pragma unroll
            for (int m = 1; m < 16; m <<= 1) {             // 16-lane argmax reduce
                float ov = __shfl_xor(bv, m, 64);
                int on = __shfl_xor(bn, m, 64);
                if (ov > bv || (ov == bv && on < bn)) { bv = ov; bn = on; }
            }
            if (q == 0) { red_val[r * 10 + w] = bv; red_idx[r * 10 + w] = bn; }
        }
    }
    __syncthreads();

    // ---- cross-wave reduce (5 waves per group, ascending col ranges) ----
    if (tid < 128) {
        int r = tid >> 1, grp = tid & 1;
        float bv = -INFINITY;
        int bn = 0;
        #pragma unroll
        for (int ww = 0; ww < 5; ++ww) {
            int wi = grp * 5 + ww;
            float v = red_val[r * 10 + wi];
            int n = red_idx[r * 10 + wi];
            if (v > bv) { bv = v; bn = n; }
        }
        atomicAdd(&cnt[bn], 1);
        sel_n[r][grp] = bn;
    }
    __syncthreads();

    // ---- gather selected embedding rows ----
    if (tid < 512) {
        int rg = tid >> 2, sub = tid & 3;
        int r = rg >> 1, grp = rg & 1;
        int n = sel_n[r][grp];
        const float4* src = (const float4*)(emb + (size_t)n * E_DIM);
        float4* dst = (float4*)(out + (size_t)(brow + r) * 512 + grp * 256);
        #pragma unroll
        for (int j = 0; j < 16; ++j)
            dst[sub + j * 4] = src[sub + j * 4];
    }
}

__global__ void ppl_kernel(const int* __restrict__ cnt, float* __restrict__ outp)
{
    const int lane = threadIdx.x;
    float total = 0.f;
    #pragma unroll
    for (int gg = 0; gg < 2; ++gg) {
        float s = 0.f;
        for (int v = lane; v < 320; v += 64) {
            float m = (float)cnt[gg * 320 + v] * (1.0f / 65536.0f);
            s += m * logf(m + 1e-7f);
        }
        #pragma unroll
        for (int msk = 1; msk <= 32; msk <<= 1) s += __shfl_xor(s, msk, 64);
        total += expf(-s);
    }
    if (lane == 0) *outp = total;
}

// ---------------- fallback fp32 path (round-1 kernel, used if ws too small) ----------------
__global__ __launch_bounds__(512) void fused_gemm_argmax(
    const float* __restrict__ hid, const float* __restrict__ noise,
    const float* __restrict__ emb, const float* __restrict__ W,
    const float* __restrict__ bias, float* __restrict__ out, int* __restrict__ cnt)
{
    __shared__ float A_lds[16][64];
    __shared__ float B_lds[16][GV + 4];
    const int tid = threadIdx.x;
    const int tx = tid & 63, ty = tid >> 6;
    const int brow = blockIdx.x * 64;
    const int nbase = tx * 10;
    float acc[8][10];
    #pragma unroll
    for (int i = 0; i < 8; ++i)
        #pragma unroll
        for (int j = 0; j < 10; ++j) acc[i][j] = 0.f;
    for (int t = 0; t < H; t += 16) {
        if (t) __syncthreads();
        if (tid < 256) {
            int m = tid & 63, kq = tid >> 6;
            float4 v = *(const float4*)(hid + (size_t)(brow + m) * H + t + kq * 4);
            A_lds[kq * 4 + 0][m] = v.x; A_lds[kq * 4 + 1][m] = v.y;
            A_lds[kq * 4 + 2][m] = v.z; A_lds[kq * 4 + 3][m] = v.w;
        }
        #pragma unroll
        for (int s = 0; s < 5; ++s) {
            int c = tid + s * 512;
            int n = c % 640, kq = c / 640;
            float4 v = *(const float4*)(W + (size_t)n * H + t + kq * 4);
            B_lds[kq * 4 + 0][n] = v.x; B_lds[kq * 4 + 1][n] = v.y;
            B_lds[kq * 4 + 2][n] = v.z; B_lds[kq * 4 + 3][n] = v.w;
        }
        __syncthreads();
        #pragma unroll 4
        for (int kk = 0; kk < 16; ++kk) {
            float a[8], bb[10];
            #pragma unroll
            for (int i = 0; i < 8; ++i) a[i] = A_lds[kk][ty * 8 + i];
            #pragma unroll
            for (int j = 0; j < 10; ++j) bb[j] = B_lds[kk][nbase + j];
            #pragma unroll
            for (int i = 0; i < 8; ++i)
                #pragma unroll
                for (int j = 0; j < 10; ++j) acc[i][j] = fmaf(a[i], bb[j], acc[i][j]);
        }
    }
    float bs[10];
    #pragma unroll
    for (int j = 0; j < 10; ++j) bs[j] = bias[nbase + j];
    const int gg = tx >> 5, ll = tx & 31;
    #pragma unroll
    for (int i = 0; i < 8; ++i) {
        const int b = brow + ty * 8 + i;
        float best = -INFINITY; int bestn = nbase;
        #pragma unroll
        for (int j = 0; j < 10; ++j) {
            float u = noise[(size_t)b * GV + nbase + j];
            float gmb = -logf(-logf(u + 1e-10f) + 1e-10f);
            float z = acc[i][j] + bs[j] + gmb;
            if (z > best) { best = z; bestn = nbase + j; }
        }
        #pragma unroll
        for (int msk = 1; msk <= 16; msk <<= 1) {
            float oz = __shfl_xor(best, msk, 64);
            int on = __shfl_xor(bestn, msk, 64);
            if (oz > best || (oz == best && on < bestn)) { best = oz; bestn = on; }
        }
        if (ll == 0) atomicAdd(&cnt[bestn], 1);
        const float4* src = (const float4*)(emb + (size_t)bestn * E_DIM);
        float4* dst = (float4*)(out + (size_t)b * 512 + gg * 256);
        dst[ll] = src[ll];
        dst[ll + 32] = src[ll + 32];
    }
}

extern "C" void kernel_launch(void* const* d_in, const int* in_sizes, int n_in,
                              void* d_out, int out_size, void* d_ws, size_t ws_size,
                              hipStream_t stream)
{
    const float* hid   = (const float*)d_in[0];
    const float* noise = (const float*)d_in[1];
    const float* emb   = (const float*)d_in[2];
    const float* W     = (const float*)d_in[3];
    const float* bias  = (const float*)d_in[4];
    float* out = (float*)d_out;
    int* cnt = (int*)d_ws;
    const int B = in_sizes[0] / H;

    hipMemsetAsync(cnt, 0, GV * sizeof(int), stream);
    if (ws_size >= (size_t)WS_NEED) {
        _Float16* wh = (_Float16*)((char*)d_ws + WS_WH);
        _Float16* wl = (_Float16*)((char*)d_ws + WS_WL);
        prep_w<<<160, 256, 0, stream>>>(W, wh, wl);
        gemm_argmax_mfma<<<B / BM, 640, 0, stream>>>(hid, noise, emb, bias, wh, wl, out, cnt);
    } else {
        fused_gemm_argmax<<<B / BM, 512, 0, stream>>>(hid, noise, emb, W, bias, out, cnt);
    }
    ppl_kernel<<<1, 64, 0, stream>>>(cnt, out + (size_t)B * 512);
}